// Round 6
// baseline (565.565 us; speedup 1.0000x reference)
//
#include <hip/hip_runtime.h>
#include <hip/hip_cooperative_groups.h>
#include <math.h>

namespace cg = cooperative_groups;

#define BATCH   4096
#define FEAT    64
#define EMB     32
#define MODELS  512
#define SEQ     128
#define KDIM    (FEAT * EMB)   // 2048

#define SQRT_MODELS 22.62741699796952f
#define LN10000     9.210340371976184f

typedef __attribute__((ext_vector_type(4))) float        f32x4;
typedef __attribute__((ext_vector_type(8))) short        bf16x8;
typedef __attribute__((ext_vector_type(4))) unsigned int u32x4;

// ws layout: Wt | pe | x | Abf   (same as R4)
#define WT_BYTES  ((size_t)MODELS * KDIM * 2)          // 2 MB   bf16 W^T, pre-scaled
#define PE_BYTES  ((size_t)SEQ * MODELS * 4)           // 256 KB pe + bias
#define X_BYTES   ((size_t)BATCH * MODELS * 4)         // 8 MB   x = A@W+b
#define ABF_BYTES ((size_t)BATCH * KDIM * 2)           // 16 MB  dense bf16 A
#define WS_MID    (WT_BYTES + PE_BYTES + X_BYTES)
#define WS_FULL   (WT_BYTES + PE_BYTES + X_BYTES + ABF_BYTES)

#define NBLK   768
#define CHUNK  2048            // rows per pipeline chunk (2 chunks)

__device__ inline unsigned short bf16_rne(float f) {
    unsigned int b = __builtin_bit_cast(unsigned int, f);
    return (unsigned short)((b + 0x7FFFu + ((b >> 16) & 1u)) >> 16);
}

#define CVT_PK4(pk, v0, v1)                                                     \
    {                                                                           \
        unsigned int q0, q1, q2, q3;                                            \
        asm("v_cvt_pk_bf16_f32 %0, %1, %2" : "=v"(q0) : "v"(v0.x), "v"(v0.y));  \
        asm("v_cvt_pk_bf16_f32 %0, %1, %2" : "=v"(q1) : "v"(v0.z), "v"(v0.w));  \
        asm("v_cvt_pk_bf16_f32 %0, %1, %2" : "=v"(q2) : "v"(v1.x), "v"(v1.y));  \
        asm("v_cvt_pk_bf16_f32 %0, %1, %2" : "=v"(q3) : "v"(v1.z), "v"(v1.w));  \
        pk = (u32x4){q0, q1, q2, q3};                                           \
    }

// ---- R4-verified dense-MFMA wave tile: 16 rows x 64 cols, K=2048 ----
// block g (0..255), 4 waves -> wave-tile t = g*4+wave over 128x8 tiles of a 2048-row chunk.
__device__ inline void gemm_tilegroup(int g, int base,
                                      const unsigned short* __restrict__ Abf,
                                      const unsigned short* __restrict__ Wt,
                                      float* __restrict__ x, int tid) {
    const int wave = tid >> 6;
    const int lane = tid & 63;
    const int ln   = lane & 15;
    const int kg   = lane >> 4;
    const int t  = g * 4 + wave;             // 0..1023
    const int m0 = base + (t >> 3) * 16;
    const int n0 = (t & 7) * 64;

    const unsigned short* ap = Abf + (size_t)(m0 + ln) * KDIM + kg * 8;
    const unsigned short* bp = Wt  + (size_t)(n0 + ln) * KDIM + kg * 8;

    f32x4 acc[4] = {f32x4{0,0,0,0}, f32x4{0,0,0,0}, f32x4{0,0,0,0}, f32x4{0,0,0,0}};

    #pragma unroll 4
    for (int k = 0; k < KDIM; k += 32) {
        const bf16x8 a = *(const bf16x8*)(ap + k);
        #pragma unroll
        for (int nf = 0; nf < 4; ++nf) {
            const bf16x8 b = *(const bf16x8*)(bp + (size_t)nf * 16 * KDIM + k);
            acc[nf] = __builtin_amdgcn_mfma_f32_16x16x32_bf16(a, b, acc[nf], 0, 0, 0);
        }
    }
    // D mapping (verified R2/R4): col = lane&15, row = (lane>>4)*4 + reg
    #pragma unroll
    for (int nf = 0; nf < 4; ++nf)
        #pragma unroll
        for (int q = 0; q < 4; ++q)
            x[(size_t)(m0 + kg * 4 + q) * MODELS + n0 + nf * 16 + ln] = acc[nf][q];
}

// ---- streamed broadcast of one output row over s in [s0, s0+ns) ----
__device__ inline void write_row_span(const float* __restrict__ x, const float* __restrict__ pe,
                                      float* __restrict__ out, int row, int s0, int ns, int tid) {
    const int col = (tid & 127) * 4;
    const int sl  = tid >> 7;                // 0..1
    const f32x4 xv = *(const f32x4*)(x + (size_t)row * MODELS + col);
    float* ob = out + (size_t)row * SEQ * MODELS + col;
    for (int s = s0 + sl; s < s0 + ns; s += 2)
        *(f32x4*)(ob + (size_t)s * MODELS) = xv + *(const f32x4*)(pe + (size_t)s * MODELS + col);
}

// ---------------- cooperative all-in-one ----------------
__global__ __launch_bounds__(256, 4)
void coop_all(const int* __restrict__ tokens, const float* __restrict__ emb,
              const float* __restrict__ W, const float* __restrict__ bias,
              unsigned short* __restrict__ Wt, float* __restrict__ pe,
              unsigned short* __restrict__ Abf, float* __restrict__ x,
              float* __restrict__ out) {
    cg::grid_group grid = cg::this_grid();
    const int bid = blockIdx.x;              // 0..767
    const int tid = threadIdx.x;

    __shared__ float t[32][33];

    // ======== S0: Wt transpose + pe table + dense gather (all independent) ========
    {
        const int tx = tid & 31, ty = tid >> 5;   // 32 x 8
        #pragma unroll 1
        for (int rep = 0; rep < 2; ++rep) {
            const int T = bid + rep * NBLK;       // tiles 0..1023
            if (T < 1024) {
                const int k0 = (T & 63) * 32, n0 = (T >> 6) * 32;
                #pragma unroll
                for (int i = 0; i < 4; ++i)
                    t[ty + i * 8][tx] = W[(size_t)(k0 + ty + i * 8) * MODELS + n0 + tx] * SQRT_MODELS;
                __syncthreads();
                #pragma unroll
                for (int i = 0; i < 4; ++i)
                    Wt[(size_t)(n0 + ty + i * 8) * KDIM + k0 + tx] = bf16_rne(t[tx][ty + i * 8]);
                __syncthreads();
            }
        }
    }
    if (bid >= 256 && bid < 512) {
        const int idx = (bid - 256) * 256 + tid;  // 0..65535
        const int s = idx >> 9, m = idx & (MODELS - 1);
        const float rate = expf(-LN10000 * (float)(2 * (m >> 1)) * (1.0f / 512.0f));
        const float ang  = (float)s * rate;
        pe[idx] = ((m & 1) ? cosf(ang) : sinf(ang)) + bias[m];
    }
    for (int u = bid * 256 + tid; u < BATCH * FEAT * 4; u += NBLK * 256) {
        const int tok = tokens[u >> 2];
        const float* src = emb + (size_t)tok * EMB + (u & 3) * 8;
        const f32x4 v0 = *(const f32x4*)src;
        const f32x4 v1 = *(const f32x4*)(src + 4);
        u32x4 pk;
        CVT_PK4(pk, v0, v1);
        *(u32x4*)(Abf + (size_t)u * 8) = pk;
    }

    grid.sync();

    // ======== S1: GEMM chunk0 (blocks 0..255) ========
    if (bid < 256) gemm_tilegroup(bid, 0, Abf, Wt, x, tid);

    grid.sync();

    // ======== S2: GEMM chunk1 (0..255)  ||  write chunk0 (256..767) ========
    if (bid < 256) {
        gemm_tilegroup(bid, CHUNK, Abf, Wt, x, tid);
    } else {
        const int wid = bid - 256;               // 0..511, exactly 4 rows each
        #pragma unroll 1
        for (int r = 0; r < 4; ++r)
            write_row_span(x, pe, out, wid * 4 + r, 0, SEQ, tid);
    }

    grid.sync();

    // ======== S3: all 768 blocks write chunk1 (row-quarter units) ========
    #pragma unroll 1
    for (int u = bid; u < CHUNK * 4; u += NBLK) {
        const int row = CHUNK + (u >> 2);
        const int q   = u & 3;
        write_row_span(x, pe, out, row, q * 32, 32, tid);
    }
}

// ================= R4 fallback pipeline (proven 278 us) =================
__global__ __launch_bounds__(256)
void prep_wt(const float* __restrict__ W, unsigned short* __restrict__ Wt) {
    __shared__ float t[32][33];
    const int k0 = blockIdx.x * 32;
    const int n0 = blockIdx.y * 32;
    const int tx = threadIdx.x;
    const int ty = threadIdx.y;
    #pragma unroll
    for (int i = 0; i < 4; ++i)
        t[ty + i * 8][tx] = W[(size_t)(k0 + ty + i * 8) * MODELS + n0 + tx] * SQRT_MODELS;
    __syncthreads();
    #pragma unroll
    for (int i = 0; i < 4; ++i)
        Wt[(size_t)(n0 + ty + i * 8) * KDIM + k0 + tx] = bf16_rne(t[tx][ty + i * 8]);
}

__global__ __launch_bounds__(256)
void prep_pe(const float* __restrict__ bias, float* __restrict__ pe) {
    const int idx = blockIdx.x * 256 + threadIdx.x;
    const int s = idx >> 9;
    const int m = idx & (MODELS - 1);
    const float rate = expf(-LN10000 * (float)(2 * (m >> 1)) * (1.0f / 512.0f));
    const float ang  = (float)s * rate;
    pe[idx] = ((m & 1) ? cosf(ang) : sinf(ang)) + bias[m];
}

__global__ __launch_bounds__(256)
void gather_a(const int* __restrict__ tokens, const float* __restrict__ emb,
              unsigned short* __restrict__ Abf) {
    const int g    = blockIdx.x * 256 + threadIdx.x;
    const int fr   = g >> 2;
    const int part = g & 3;
    const int tok  = tokens[fr];
    const float* src = emb + (size_t)tok * EMB + part * 8;
    const f32x4 v0 = *(const f32x4*)src;
    const f32x4 v1 = *(const f32x4*)(src + 4);
    u32x4 pk;
    CVT_PK4(pk, v0, v1);
    *(u32x4*)(Abf + (size_t)g * 8) = pk;
}

__global__ __launch_bounds__(256)
void gemm_dense(const unsigned short* __restrict__ Abf,
                const unsigned short* __restrict__ Wt,
                float* __restrict__ x) {
    const int tid  = threadIdx.x;
    const int lane = tid & 63;
    const int wave = tid >> 6;
    const int ln   = lane & 15;
    const int kg   = lane >> 4;
    const int m0 = blockIdx.y * 64 + (wave >> 1) * 32;
    const int n0 = blockIdx.x * 64 + (wave & 1) * 32;

    const unsigned short* a0p = Abf + (size_t)(m0 + ln) * KDIM + kg * 8;
    const unsigned short* a1p = a0p + 16 * KDIM;
    const unsigned short* b0p = Wt + (size_t)(n0 + ln) * KDIM + kg * 8;
    const unsigned short* b1p = b0p + 16 * KDIM;

    f32x4 acc00 = {0,0,0,0}, acc01 = {0,0,0,0};
    f32x4 acc10 = {0,0,0,0}, acc11 = {0,0,0,0};

    #pragma unroll 4
    for (int k = 0; k < KDIM; k += 32) {
        const bf16x8 a0 = *(const bf16x8*)(a0p + k);
        const bf16x8 a1 = *(const bf16x8*)(a1p + k);
        const bf16x8 b0 = *(const bf16x8*)(b0p + k);
        const bf16x8 b1 = *(const bf16x8*)(b1p + k);
        acc00 = __builtin_amdgcn_mfma_f32_16x16x32_bf16(a0, b0, acc00, 0, 0, 0);
        acc01 = __builtin_amdgcn_mfma_f32_16x16x32_bf16(a0, b1, acc01, 0, 0, 0);
        acc10 = __builtin_amdgcn_mfma_f32_16x16x32_bf16(a1, b0, acc10, 0, 0, 0);
        acc11 = __builtin_amdgcn_mfma_f32_16x16x32_bf16(a1, b1, acc11, 0, 0, 0);
    }
    #pragma unroll
    for (int q = 0; q < 4; ++q) {
        const int r = kg * 4 + q;
        x[(size_t)(m0 + r)      * MODELS + n0 + ln]      = acc00[q];
        x[(size_t)(m0 + r)      * MODELS + n0 + 16 + ln] = acc01[q];
        x[(size_t)(m0 + 16 + r) * MODELS + n0 + ln]      = acc10[q];
        x[(size_t)(m0 + 16 + r) * MODELS + n0 + 16 + ln] = acc11[q];
    }
}

__global__ __launch_bounds__(256)
void bcast_pe(const float* __restrict__ x, const float* __restrict__ pe,
              float* __restrict__ out) {
    const int tid = threadIdx.x;
    const int m4  = tid & 127;
    const int b   = blockIdx.x * 2 + (tid >> 7);
    const f32x4 xv = *(const f32x4*)(x + (size_t)b * MODELS + m4 * 4);
    const f32x4* pev = (const f32x4*)pe;
    float* ob = out + (size_t)b * SEQ * MODELS + m4 * 4;
    #pragma unroll 4
    for (int s = 0; s < SEQ; ++s) {
        const f32x4 p = pev[s * 128 + m4];
        *(f32x4*)(ob + (size_t)s * MODELS) = xv + p;
    }
}

// ---------------- last-resort fallback: verified round-1 fused kernel ----------------
#define BM 64
#define BN 64
#define BK 32
__global__ __launch_bounds__(256, 2)
void fused_emb_gemm_pe(const int* __restrict__ tokens, const float* __restrict__ emb,
                       const float* __restrict__ W, const float* __restrict__ bias,
                       float* __restrict__ out) {
    __shared__ float As[BK][BM];
    __shared__ float Bs[BK][BN];
    __shared__ float peS[SEQ][BN];
    const int tid  = threadIdx.x;
    const int bn   = blockIdx.x * BN;
    const int brow = blockIdx.y * BM;
    for (int idx = tid; idx < SEQ * BN; idx += 256) {
        const int s  = idx >> 6;
        const int ml = idx & 63;
        const int m  = bn + ml;
        const float rate = expf(-LN10000 * (float)(2 * (m >> 1)) * (1.0f / 512.0f));
        const float ang  = (float)s * rate;
        peS[s][ml] = (m & 1) ? cosf(ang) : sinf(ang);
    }
    float acc[4][4] = {};
    const int tx = tid & 15;
    const int ty = tid >> 4;
    const int lr = tid >> 2;
    const int lj = tid & 3;
    const int bk = tid >> 4;
    const int bc = (tid & 15) * 4;
    for (int kt = 0; kt < FEAT; ++kt) {
        __syncthreads();
        {
            const int tok = tokens[(brow + lr) * FEAT + kt];
            const float* erow = emb + (size_t)tok * EMB + lj * 8;
            const float4 a0 = *(const float4*)(erow);
            const float4 a1 = *(const float4*)(erow + 4);
            const int k0 = lj * 8;
            As[k0 + 0][lr] = a0.x * SQRT_MODELS; As[k0 + 1][lr] = a0.y * SQRT_MODELS;
            As[k0 + 2][lr] = a0.z * SQRT_MODELS; As[k0 + 3][lr] = a0.w * SQRT_MODELS;
            As[k0 + 4][lr] = a1.x * SQRT_MODELS; As[k0 + 5][lr] = a1.y * SQRT_MODELS;
            As[k0 + 6][lr] = a1.z * SQRT_MODELS; As[k0 + 7][lr] = a1.w * SQRT_MODELS;
        }
        {
            const float* w0 = W + (size_t)(kt * 32 + bk) * MODELS + bn + bc;
            const float* w1 = W + (size_t)(kt * 32 + bk + 16) * MODELS + bn + bc;
            *(float4*)&Bs[bk][bc]      = *(const float4*)w0;
            *(float4*)&Bs[bk + 16][bc] = *(const float4*)w1;
        }
        __syncthreads();
        #pragma unroll
        for (int k = 0; k < BK; ++k) {
            const float4 a = *(const float4*)&As[k][ty * 4];
            const float4 b = *(const float4*)&Bs[k][tx * 4];
            acc[0][0] += a.x * b.x; acc[0][1] += a.x * b.y; acc[0][2] += a.x * b.z; acc[0][3] += a.x * b.w;
            acc[1][0] += a.y * b.x; acc[1][1] += a.y * b.y; acc[1][2] += a.y * b.z; acc[1][3] += a.y * b.w;
            acc[2][0] += a.z * b.x; acc[2][1] += a.z * b.y; acc[2][2] += a.z * b.z; acc[2][3] += a.z * b.w;
            acc[3][0] += a.w * b.x; acc[3][1] += a.w * b.y; acc[3][2] += a.w * b.z; acc[3][3] += a.w * b.w;
        }
    }
    {
        const float4 bv = *(const float4*)(bias + bn + tx * 4);
        #pragma unroll
        for (int i = 0; i < 4; ++i) {
            acc[i][0] += bv.x; acc[i][1] += bv.y; acc[i][2] += bv.z; acc[i][3] += bv.w;
        }
    }
    size_t rowbase[4];
    #pragma unroll
    for (int i = 0; i < 4; ++i)
        rowbase[i] = ((size_t)(brow + ty * 4 + i) * SEQ) * MODELS + bn + tx * 4;
    #pragma unroll 4
    for (int s = 0; s < SEQ; ++s) {
        const float4 pv = *(const float4*)&peS[s][tx * 4];
        const size_t soff = (size_t)s * MODELS;
        #pragma unroll
        for (int i = 0; i < 4; ++i) {
            float4 o;
            o.x = acc[i][0] + pv.x; o.y = acc[i][1] + pv.y;
            o.z = acc[i][2] + pv.z; o.w = acc[i][3] + pv.w;
            *(float4*)(out + rowbase[i] + soff) = o;
        }
    }
}

static void launch_r4(const int* tokens, const float* emb, const float* W,
                      const float* bias, float* out, char* w, hipStream_t stream) {
    unsigned short* Wt  = (unsigned short*)w;
    float*          pe  = (float*)(w + WT_BYTES);
    float*          x   = (float*)(w + WT_BYTES + PE_BYTES);
    unsigned short* Abf = (unsigned short*)(w + WT_BYTES + PE_BYTES + X_BYTES);
    prep_wt<<<dim3(KDIM / 32, MODELS / 32), dim3(32, 8), 0, stream>>>(W, Wt);
    prep_pe<<<dim3(SEQ * MODELS / 256), dim3(256), 0, stream>>>(bias, pe);
    gather_a<<<dim3(BATCH * KDIM / 8 / 256), dim3(256), 0, stream>>>(tokens, emb, Abf);
    gemm_dense<<<dim3(MODELS / 64, BATCH / 64), dim3(256), 0, stream>>>(Abf, Wt, x);
    bcast_pe<<<dim3(BATCH / 2), dim3(256), 0, stream>>>(x, pe, out);
}

extern "C" void kernel_launch(void* const* d_in, const int* in_sizes, int n_in,
                              void* d_out, int out_size, void* d_ws, size_t ws_size,
                              hipStream_t stream) {
    const int*   tokens = (const int*)d_in[0];
    const float* emb    = (const float*)d_in[1];
    const float* W      = (const float*)d_in[2];
    const float* bias   = (const float*)d_in[3];
    float*       out    = (float*)d_out;

    if (ws_size >= WS_FULL) {
        char* w = (char*)d_ws;
        unsigned short* Wt  = (unsigned short*)w;
        float*          pe  = (float*)(w + WT_BYTES);
        float*          x   = (float*)(w + WT_BYTES + PE_BYTES);
        unsigned short* Abf = (unsigned short*)(w + WT_BYTES + PE_BYTES + X_BYTES);

        int dev = 0, coop = 0;
        hipGetDevice(&dev);
        hipDeviceGetAttribute(&coop, hipDeviceAttributeCooperativeLaunch, dev);

        if (coop) {
            void* args[] = {(void*)&tokens, (void*)&emb, (void*)&W, (void*)&bias,
                            (void*)&Wt, (void*)&pe, (void*)&Abf, (void*)&x, (void*)&out};
            hipError_t e = hipLaunchCooperativeKernel((const void*)coop_all, dim3(NBLK),
                                                      dim3(256), args, 0, stream);
            if (e != hipSuccess) {
                (void)hipGetLastError();   // clear sticky error, fall back
                launch_r4(tokens, emb, W, bias, out, w, stream);
            }
        } else {
            launch_r4(tokens, emb, W, bias, out, w, stream);
        }
    } else {
        fused_emb_gemm_pe<<<dim3(MODELS / BN, BATCH / BM), dim3(256), 0, stream>>>(
            tokens, emb, W, bias, out);
    }
}

// Round 7
// 273.511 us; speedup vs baseline: 2.0678x; 2.0678x over previous
//
#include <hip/hip_runtime.h>
#include <math.h>

#define BATCH   4096
#define FEAT    64
#define EMB     32
#define MODELS  512
#define SEQ     128
#define KDIM    (FEAT * EMB)   // 2048

#define SQRT_MODELS 22.62741699796952f
#define LN10000     9.210340371976184f

typedef __attribute__((ext_vector_type(4))) float        f32x4;
typedef __attribute__((ext_vector_type(8))) short        bf16x8;
typedef __attribute__((ext_vector_type(4))) unsigned int u32x4;

// ws layout: Wt | pe | x | Abf   (same as R4)
#define WT_BYTES  ((size_t)MODELS * KDIM * 2)          // 2 MB   bf16 W^T, pre-scaled
#define PE_BYTES  ((size_t)SEQ * MODELS * 4)           // 256 KB pe + bias
#define X_BYTES   ((size_t)BATCH * MODELS * 4)         // 8 MB   x = A@W+b
#define ABF_BYTES ((size_t)BATCH * KDIM * 2)           // 16 MB  dense bf16 A
#define WS_MID    (WT_BYTES + PE_BYTES + X_BYTES)
#define WS_FULL   (WT_BYTES + PE_BYTES + X_BYTES + ABF_BYTES)

__device__ inline unsigned short bf16_rne(float f) {
    unsigned int b = __builtin_bit_cast(unsigned int, f);
    return (unsigned short)((b + 0x7FFFu + ((b >> 16) & 1u)) >> 16);
}

#define CVT_PK4(pk, v0, v1)                                                     \
    {                                                                           \
        unsigned int q0, q1, q2, q3;                                            \
        asm("v_cvt_pk_bf16_f32 %0, %1, %2" : "=v"(q0) : "v"(v0.x), "v"(v0.y));  \
        asm("v_cvt_pk_bf16_f32 %0, %1, %2" : "=v"(q1) : "v"(v0.z), "v"(v0.w));  \
        asm("v_cvt_pk_bf16_f32 %0, %1, %2" : "=v"(q2) : "v"(v1.x), "v"(v1.y));  \
        asm("v_cvt_pk_bf16_f32 %0, %1, %2" : "=v"(q3) : "v"(v1.z), "v"(v1.w));  \
        pk = (u32x4){q0, q1, q2, q3};                                           \
    }

// ---------------- prep_all: Wt transpose | pe table | dense gather, one launch ----------------
// blocks [0,1024): Wt 32x32 transpose tiles      (verified R2/R4 logic)
// blocks [1024,1280): pe[s][m] + bias            (verified R2/R4 logic)
// blocks [1280,5376): gather Abf, 16B/thread     (verified R4 logic)
__global__ __launch_bounds__(256)
void prep_all(const int* __restrict__ tokens, const float* __restrict__ emb,
              const float* __restrict__ W, const float* __restrict__ bias,
              unsigned short* __restrict__ Wt, float* __restrict__ pe,
              unsigned short* __restrict__ Abf) {
    const int bx  = blockIdx.x;
    const int tid = threadIdx.x;

    if (bx < 1024) {
        // Wt[n][k] = W[k][n] * sqrt(512), bf16
        __shared__ float t[32][33];
        const int k0 = (bx & 63) * 32;
        const int n0 = (bx >> 6) * 32;
        const int tx = tid & 31;
        const int ty = tid >> 5;            // 0..7
        #pragma unroll
        for (int i = 0; i < 4; ++i)
            t[ty + i * 8][tx] = W[(size_t)(k0 + ty + i * 8) * MODELS + n0 + tx] * SQRT_MODELS;
        __syncthreads();
        #pragma unroll
        for (int i = 0; i < 4; ++i)
            Wt[(size_t)(n0 + ty + i * 8) * KDIM + k0 + tx] = bf16_rne(t[tx][ty + i * 8]);
    } else if (bx < 1280) {
        const int idx = (bx - 1024) * 256 + tid;      // 0..65535
        const int s = idx >> 9;
        const int m = idx & (MODELS - 1);
        const float rate = expf(-LN10000 * (float)(2 * (m >> 1)) * (1.0f / 512.0f));
        const float ang  = (float)s * rate;
        pe[idx] = ((m & 1) ? cosf(ang) : sinf(ang)) + bias[m];
    } else {
        const int g    = (bx - 1280) * 256 + tid;     // 0 .. 1M-1
        const int fr   = g >> 2;                      // row*64 + feature
        const int part = g & 3;
        const int tok  = tokens[fr];
        const float* src = emb + (size_t)tok * EMB + part * 8;
        const f32x4 v0 = *(const f32x4*)src;
        const f32x4 v1 = *(const f32x4*)(src + 4);
        u32x4 pk;
        CVT_PK4(pk, v0, v1);
        *(u32x4*)(Abf + (size_t)g * 8) = pk;
    }
}

// ---------------- GEMM: x = Abf @ Wt^T  (verified R4, unchanged) ----------------
__global__ __launch_bounds__(256)
void gemm_dense(const unsigned short* __restrict__ Abf,
                const unsigned short* __restrict__ Wt,
                float* __restrict__ x) {
    const int tid  = threadIdx.x;
    const int lane = tid & 63;
    const int wave = tid >> 6;
    const int ln   = lane & 15;
    const int kg   = lane >> 4;
    const int m0 = blockIdx.y * 64 + (wave >> 1) * 32;
    const int n0 = blockIdx.x * 64 + (wave & 1) * 32;

    const unsigned short* a0p = Abf + (size_t)(m0 + ln) * KDIM + kg * 8;
    const unsigned short* a1p = a0p + 16 * KDIM;
    const unsigned short* b0p = Wt + (size_t)(n0 + ln) * KDIM + kg * 8;
    const unsigned short* b1p = b0p + 16 * KDIM;

    f32x4 acc00 = {0,0,0,0}, acc01 = {0,0,0,0};
    f32x4 acc10 = {0,0,0,0}, acc11 = {0,0,0,0};

    #pragma unroll 4
    for (int k = 0; k < KDIM; k += 32) {
        const bf16x8 a0 = *(const bf16x8*)(a0p + k);
        const bf16x8 a1 = *(const bf16x8*)(a1p + k);
        const bf16x8 b0 = *(const bf16x8*)(b0p + k);
        const bf16x8 b1 = *(const bf16x8*)(b1p + k);
        acc00 = __builtin_amdgcn_mfma_f32_16x16x32_bf16(a0, b0, acc00, 0, 0, 0);
        acc01 = __builtin_amdgcn_mfma_f32_16x16x32_bf16(a0, b1, acc01, 0, 0, 0);
        acc10 = __builtin_amdgcn_mfma_f32_16x16x32_bf16(a1, b0, acc10, 0, 0, 0);
        acc11 = __builtin_amdgcn_mfma_f32_16x16x32_bf16(a1, b1, acc11, 0, 0, 0);
    }
    // D mapping (verified): col = lane&15, row = (lane>>4)*4 + reg
    #pragma unroll
    for (int q = 0; q < 4; ++q) {
        const int r = kg * 4 + q;
        x[(size_t)(m0 + r)      * MODELS + n0 + ln]      = acc00[q];
        x[(size_t)(m0 + r)      * MODELS + n0 + 16 + ln] = acc01[q];
        x[(size_t)(m0 + 16 + r) * MODELS + n0 + ln]      = acc10[q];
        x[(size_t)(m0 + 16 + r) * MODELS + n0 + 16 + ln] = acc11[q];
    }
}

// ---------------- bcast: out[b][s][m] = x[b][m] + pe[s][m], NT stores ----------------
__global__ __launch_bounds__(256)
void bcast_pe(const float* __restrict__ x, const float* __restrict__ pe,
              float* __restrict__ out) {
    const int tid = threadIdx.x;
    const int m4  = tid & 127;
    const int b   = blockIdx.x * 2 + (tid >> 7);
    const f32x4 xv = *(const f32x4*)(x + (size_t)b * MODELS + m4 * 4);
    const f32x4* pev = (const f32x4*)pe;
    float* ob = out + (size_t)b * SEQ * MODELS + m4 * 4;
    #pragma unroll 8
    for (int s = 0; s < SEQ; ++s) {
        const f32x4 p = pev[s * 128 + m4];
        __builtin_nontemporal_store(xv + p, (f32x4*)(ob + (size_t)s * MODELS));
    }
}

// ---------------- mid-path GEMM (proven R2): gather-direct MFMA ----------------
__global__ __launch_bounds__(256)
void gemm_mfma(const int* __restrict__ tokens, const float* __restrict__ emb,
               const unsigned short* __restrict__ Wt, float* __restrict__ x) {
    const int tid  = threadIdx.x;
    const int wave = tid >> 6;
    const int lane = tid & 63;
    const int ln   = lane & 15;
    const int kg   = lane >> 4;
    const int m_base = blockIdx.y * 16;
    const int n_base = blockIdx.x * 256 + wave * 64;
    const int* trow = tokens + (size_t)(m_base + ln) * FEAT;
    const unsigned short* bptr[4];
    #pragma unroll
    for (int nf = 0; nf < 4; ++nf)
        bptr[nf] = Wt + (size_t)(n_base + nf * 16 + ln) * KDIM + kg * 8;
    f32x4 acc[4] = {f32x4{0,0,0,0}, f32x4{0,0,0,0}, f32x4{0,0,0,0}, f32x4{0,0,0,0}};
    for (int f4 = 0; f4 < FEAT; f4 += 4) {
        const int4 tok4 = *(const int4*)(trow + f4);
        const int toks[4] = {tok4.x, tok4.y, tok4.z, tok4.w};
        #pragma unroll
        for (int j = 0; j < 4; ++j) {
            const int f = f4 + j;
            const float* ea = emb + (size_t)toks[j] * EMB + kg * 8;
            const f32x4 a0 = *(const f32x4*)ea;
            const f32x4 a1 = *(const f32x4*)(ea + 4);
            u32x4 pk;
            CVT_PK4(pk, a0, a1);
            const bf16x8 afrag = __builtin_bit_cast(bf16x8, pk);
            #pragma unroll
            for (int nf = 0; nf < 4; ++nf) {
                const bf16x8 bfrag = *(const bf16x8*)(bptr[nf] + (size_t)f * EMB);
                acc[nf] = __builtin_amdgcn_mfma_f32_16x16x32_bf16(afrag, bfrag, acc[nf], 0, 0, 0);
            }
        }
    }
    #pragma unroll
    for (int nf = 0; nf < 4; ++nf)
        #pragma unroll
        for (int q = 0; q < 4; ++q)
            x[(size_t)(m_base + kg * 4 + q) * MODELS + n_base + nf * 16 + ln] = acc[nf][q];
}

__global__ __launch_bounds__(256)
void prep_wt(const float* __restrict__ W, unsigned short* __restrict__ Wt) {
    __shared__ float t[32][33];
    const int k0 = blockIdx.x * 32;
    const int n0 = blockIdx.y * 32;
    const int tx = threadIdx.x;
    const int ty = threadIdx.y;
    #pragma unroll
    for (int i = 0; i < 4; ++i)
        t[ty + i * 8][tx] = W[(size_t)(k0 + ty + i * 8) * MODELS + n0 + tx] * SQRT_MODELS;
    __syncthreads();
    #pragma unroll
    for (int i = 0; i < 4; ++i)
        Wt[(size_t)(n0 + ty + i * 8) * KDIM + k0 + tx] = bf16_rne(t[tx][ty + i * 8]);
}

__global__ __launch_bounds__(256)
void prep_pe(const float* __restrict__ bias, float* __restrict__ pe) {
    const int idx = blockIdx.x * 256 + threadIdx.x;
    const int s = idx >> 9;
    const int m = idx & (MODELS - 1);
    const float rate = expf(-LN10000 * (float)(2 * (m >> 1)) * (1.0f / 512.0f));
    const float ang  = (float)s * rate;
    pe[idx] = ((m & 1) ? cosf(ang) : sinf(ang)) + bias[m];
}

// ---------------- last-resort fallback: verified round-1 fused kernel ----------------
#define BM 64
#define BN 64
#define BK 32
__global__ __launch_bounds__(256, 2)
void fused_emb_gemm_pe(const int* __restrict__ tokens, const float* __restrict__ emb,
                       const float* __restrict__ W, const float* __restrict__ bias,
                       float* __restrict__ out) {
    __shared__ float As[BK][BM];
    __shared__ float Bs[BK][BN];
    __shared__ float peS[SEQ][BN];
    const int tid  = threadIdx.x;
    const int bn   = blockIdx.x * BN;
    const int brow = blockIdx.y * BM;
    for (int idx = tid; idx < SEQ * BN; idx += 256) {
        const int s  = idx >> 6;
        const int ml = idx & 63;
        const int m  = bn + ml;
        const float rate = expf(-LN10000 * (float)(2 * (m >> 1)) * (1.0f / 512.0f));
        const float ang  = (float)s * rate;
        peS[s][ml] = (m & 1) ? cosf(ang) : sinf(ang);
    }
    float acc[4][4] = {};
    const int tx = tid & 15;
    const int ty = tid >> 4;
    const int lr = tid >> 2;
    const int lj = tid & 3;
    const int bk = tid >> 4;
    const int bc = (tid & 15) * 4;
    for (int kt = 0; kt < FEAT; ++kt) {
        __syncthreads();
        {
            const int tok = tokens[(brow + lr) * FEAT + kt];
            const float* erow = emb + (size_t)tok * EMB + lj * 8;
            const float4 a0 = *(const float4*)(erow);
            const float4 a1 = *(const float4*)(erow + 4);
            const int k0 = lj * 8;
            As[k0 + 0][lr] = a0.x * SQRT_MODELS; As[k0 + 1][lr] = a0.y * SQRT_MODELS;
            As[k0 + 2][lr] = a0.z * SQRT_MODELS; As[k0 + 3][lr] = a0.w * SQRT_MODELS;
            As[k0 + 4][lr] = a1.x * SQRT_MODELS; As[k0 + 5][lr] = a1.y * SQRT_MODELS;
            As[k0 + 6][lr] = a1.z * SQRT_MODELS; As[k0 + 7][lr] = a1.w * SQRT_MODELS;
        }
        {
            const float* w0 = W + (size_t)(kt * 32 + bk) * MODELS + bn + bc;
            const float* w1 = W + (size_t)(kt * 32 + bk + 16) * MODELS + bn + bc;
            *(float4*)&Bs[bk][bc]      = *(const float4*)w0;
            *(float4*)&Bs[bk + 16][bc] = *(const float4*)w1;
        }
        __syncthreads();
        #pragma unroll
        for (int k = 0; k < BK; ++k) {
            const float4 a = *(const float4*)&As[k][ty * 4];
            const float4 b = *(const float4*)&Bs[k][tx * 4];
            acc[0][0] += a.x * b.x; acc[0][1] += a.x * b.y; acc[0][2] += a.x * b.z; acc[0][3] += a.x * b.w;
            acc[1][0] += a.y * b.x; acc[1][1] += a.y * b.y; acc[1][2] += a.y * b.z; acc[1][3] += a.y * b.w;
            acc[2][0] += a.z * b.x; acc[2][1] += a.z * b.y; acc[2][2] += a.z * b.z; acc[2][3] += a.z * b.w;
            acc[3][0] += a.w * b.x; acc[3][1] += a.w * b.y; acc[3][2] += a.w * b.z; acc[3][3] += a.w * b.w;
        }
    }
    {
        const float4 bv = *(const float4*)(bias + bn + tx * 4);
        #pragma unroll
        for (int i = 0; i < 4; ++i) {
            acc[i][0] += bv.x; acc[i][1] += bv.y; acc[i][2] += bv.z; acc[i][3] += bv.w;
        }
    }
    size_t rowbase[4];
    #pragma unroll
    for (int i = 0; i < 4; ++i)
        rowbase[i] = ((size_t)(brow + ty * 4 + i) * SEQ) * MODELS + bn + tx * 4;
    #pragma unroll 4
    for (int s = 0; s < SEQ; ++s) {
        const float4 pv = *(const float4*)&peS[s][tx * 4];
        const size_t soff = (size_t)s * MODELS;
        #pragma unroll
        for (int i = 0; i < 4; ++i) {
            float4 o;
            o.x = acc[i][0] + pv.x; o.y = acc[i][1] + pv.y;
            o.z = acc[i][2] + pv.z; o.w = acc[i][3] + pv.w;
            *(float4*)(out + rowbase[i] + soff) = o;
        }
    }
}

extern "C" void kernel_launch(void* const* d_in, const int* in_sizes, int n_in,
                              void* d_out, int out_size, void* d_ws, size_t ws_size,
                              hipStream_t stream) {
    const int*   tokens = (const int*)d_in[0];
    const float* emb    = (const float*)d_in[1];
    const float* W      = (const float*)d_in[2];
    const float* bias   = (const float*)d_in[3];
    float*       out    = (float*)d_out;

    if (ws_size >= WS_FULL) {
        char* w = (char*)d_ws;
        unsigned short* Wt  = (unsigned short*)w;
        float*          pe  = (float*)(w + WT_BYTES);
        float*          x   = (float*)(w + WT_BYTES + PE_BYTES);
        unsigned short* Abf = (unsigned short*)(w + WT_BYTES + PE_BYTES + X_BYTES);

        prep_all<<<dim3(1024 + 256 + 4096), dim3(256), 0, stream>>>(
            tokens, emb, W, bias, Wt, pe, Abf);
        gemm_dense<<<dim3(MODELS / 64, BATCH / 64), dim3(256), 0, stream>>>(Abf, Wt, x);
        bcast_pe<<<dim3(BATCH / 2), dim3(256), 0, stream>>>(x, pe, out);
    } else if (ws_size >= WS_MID) {
        char* w = (char*)d_ws;
        unsigned short* Wt = (unsigned short*)w;
        float* pe = (float*)(w + WT_BYTES);
        float* x  = (float*)(w + WT_BYTES + PE_BYTES);

        prep_wt<<<dim3(KDIM / 32, MODELS / 32), dim3(32, 8), 0, stream>>>(W, Wt);
        prep_pe<<<dim3(SEQ * MODELS / 256), dim3(256), 0, stream>>>(bias, pe);
        gemm_mfma<<<dim3(MODELS / 256, BATCH / 16), dim3(256), 0, stream>>>(tokens, emb, Wt, x);
        bcast_pe<<<dim3(BATCH / 2), dim3(256), 0, stream>>>(x, pe, out);
    } else {
        fused_emb_gemm_pe<<<dim3(MODELS / BN, BATCH / BM), dim3(256), 0, stream>>>(
            tokens, emb, W, bias, out);
    }
}